// Round 1
// baseline (305.771 us; speedup 1.0000x reference)
//
#include <hip/hip_runtime.h>
#include <hip/hip_bf16.h>

#define BB 2
#define SS 2048
#define HH 16
#define DD 64

typedef __bf16 bf16x8 __attribute__((ext_vector_type(8)));
typedef float f32x4 __attribute__((ext_vector_type(4)));

// ---------------------------------------------------------------------------
// Kernel 1: fused Q/K/V projection.  x:[B,S,H,D] f32  ->  [B,H,S,D] bf16
// q[e] = sum_d x[d] * W[e][d] + b[e]   (torch Linear: x @ W.T + b)
// ---------------------------------------------------------------------------
__global__ __launch_bounds__(256) void proj_kernel(
    const float* __restrict__ xq, const float* __restrict__ xk,
    const float* __restrict__ xv,
    const float* __restrict__ Wq, const float* __restrict__ bq,
    const float* __restrict__ Wk, const float* __restrict__ bk,
    const float* __restrict__ Wv, const float* __restrict__ bv,
    __hip_bfloat16* __restrict__ Qp, __hip_bfloat16* __restrict__ Kp,
    __hip_bfloat16* __restrict__ Vp)
{
    __shared__ float w_lds[3][64][65];   // [mat][d][e], padded: reads by e conflict-free
    __shared__ float bias[3][64];
    const int tid = threadIdx.x;
    for (int i = tid; i < 4096; i += 256) {
        const int e = i >> 6, d = i & 63;
        w_lds[0][d][e] = Wq[i];
        w_lds[1][d][e] = Wk[i];
        w_lds[2][d][e] = Wv[i];
    }
    if (tid < 64) {
        bias[0][tid] = bq[tid];
        bias[1][tid] = bk[tid];
        bias[2][tid] = bv[tid];
    }
    __syncthreads();

    const int e = tid & 63;
    const int rg = tid >> 6;
    for (int it = 0; it < 16; ++it) {
        const int r = blockIdx.x * 64 + rg * 16 + it;   // global row in [B*S*H)
        const int b = r >> 15;            // / (S*H) = 32768
        const int s = (r >> 4) & (SS - 1);
        const int h = r & (HH - 1);
        const size_t xoff = (size_t)r * DD;
        float aq = bias[0][e], ak = bias[1][e], av = bias[2][e];
#pragma unroll 8
        for (int d = 0; d < DD; ++d) {
            aq += xq[xoff + d] * w_lds[0][d][e];
            ak += xk[xoff + d] * w_lds[1][d][e];
            av += xv[xoff + d] * w_lds[2][d][e];
        }
        const size_t oo = (((size_t)(b * HH + h) * SS) + s) * DD + e;
        Qp[oo] = __float2bfloat16(aq);
        Kp[oo] = __float2bfloat16(ak);
        Vp[oo] = __float2bfloat16(av);
    }
}

// ---------------------------------------------------------------------------
// Kernel 2: flash attention, bf16 MFMA 16x16x32, fp32 accumulate.
// grid = (B*H, S/64); block = 256 (4 waves); wave w owns q-rows [qt*64+w*16, +16)
// ---------------------------------------------------------------------------
__global__ __launch_bounds__(256) void attn_kernel(
    const __hip_bfloat16* __restrict__ Qp, const __hip_bfloat16* __restrict__ Kp,
    const __hip_bfloat16* __restrict__ Vp, const float* __restrict__ mask,
    const float* __restrict__ inv_scale_p, float* __restrict__ out)
{
    constexpr int TT = 64;        // t-tile
    constexpr int VP = TT + 8;    // padded stride (144 B rows, 16B-aligned)
    __shared__ __attribute__((aligned(16))) __hip_bfloat16 v_lds[DD][VP];     // V^T: [d][t]
    __shared__ __attribute__((aligned(16))) __hip_bfloat16 p_lds[4][16][VP];  // per-wave P: [q][t]

    const int tid = threadIdx.x;
    const int lane = tid & 63;
    const int wave = tid >> 6;
    const int lm = lane & 15;
    const int lg = lane >> 4;
    const int bh = blockIdx.x;
    const int qt = blockIdx.y;
    const int b = bh >> 4;
    const float scale = 1.0f / inv_scale_p[0];

    const __hip_bfloat16* Qb = Qp + (size_t)bh * SS * DD;
    const __hip_bfloat16* Kb = Kp + (size_t)bh * SS * DD;
    const __hip_bfloat16* Vb = Vp + (size_t)bh * SS * DD;
    const float* maskb = mask + (size_t)b * SS * SS;

    const int q0 = qt * 64 + wave * 16;

    // Q fragments live in registers for the whole kernel.
    // A-frag layout: row = lane&15, k = kc*32 + (lane>>4)*8 + i
    bf16x8 qf[2];
    {
        const __hip_bfloat16* qptr = Qb + (size_t)(q0 + lm) * DD + lg * 8;
        qf[0] = *reinterpret_cast<const bf16x8*>(qptr);
        qf[1] = *reinterpret_cast<const bf16x8*>(qptr + 32);
    }

    f32x4 o[4];
    float m_r[4], l_r[4];
#pragma unroll
    for (int i = 0; i < 4; ++i) { o[i] = f32x4{0.f, 0.f, 0.f, 0.f}; m_r[i] = -1e30f; l_r[i] = 0.f; }

    for (int t0 = 0; t0 < SS; t0 += TT) {
        __syncthreads();   // protect v_lds from previous iteration's readers
        // ---- stage V^T into LDS (cooperative, vectorized global reads) ----
#pragma unroll
        for (int k = 0; k < 2; ++k) {
            const int base = (tid + k * 256) * 8;   // element idx in 64x64 tile
            const int tt = base >> 6, d0 = base & 63;
            bf16x8 vv = *reinterpret_cast<const bf16x8*>(Vb + (size_t)(t0 + tt) * DD + d0);
#pragma unroll
            for (int j = 0; j < 8; ++j)
                v_lds[d0 + j][tt] = *(((const __hip_bfloat16*)&vv) + j);
        }

        // ---- scores: S[q][t] = sum_d Q[q][d] K[t][d] ----
        f32x4 s[4];
#pragma unroll
        for (int nt = 0; nt < 4; ++nt) s[nt] = f32x4{0.f, 0.f, 0.f, 0.f};
#pragma unroll
        for (int kc = 0; kc < 2; ++kc) {
#pragma unroll
            for (int nt = 0; nt < 4; ++nt) {
                bf16x8 kf = *reinterpret_cast<const bf16x8*>(
                    Kb + (size_t)(t0 + nt * 16 + lm) * DD + kc * 32 + lg * 8);
                s[nt] = __builtin_amdgcn_mfma_f32_16x16x32_bf16(qf[kc], kf, s[nt], 0, 0, 0);
            }
        }

        // ---- scale + mask.  C layout: col = lane&15 (t), row = lg*4+r (q) ----
        float sv[4][4];
#pragma unroll
        for (int nt = 0; nt < 4; ++nt)
#pragma unroll
            for (int r = 0; r < 4; ++r)
                sv[nt][r] = s[nt][r] * scale +
                            maskb[(size_t)(q0 + lg * 4 + r) * SS + t0 + nt * 16 + lm];

        // ---- online softmax update ----
        float pv[4][4];
#pragma unroll
        for (int r = 0; r < 4; ++r) {
            float mx = fmaxf(fmaxf(sv[0][r], sv[1][r]), fmaxf(sv[2][r], sv[3][r]));
#pragma unroll
            for (int off = 1; off < 16; off <<= 1) mx = fmaxf(mx, __shfl_xor(mx, off));
            const float mn = fmaxf(m_r[r], mx);
            const float alpha = __expf(m_r[r] - mn);
            m_r[r] = mn;
            float rs = 0.f;
#pragma unroll
            for (int nt = 0; nt < 4; ++nt) {
                const float p = __expf(sv[nt][r] - mn);
                pv[nt][r] = p;
                rs += p;
            }
#pragma unroll
            for (int off = 1; off < 16; off <<= 1) rs += __shfl_xor(rs, off);
            l_r[r] = l_r[r] * alpha + rs;
            o[0][r] *= alpha; o[1][r] *= alpha; o[2][r] *= alpha; o[3][r] *= alpha;
        }

        // ---- P -> LDS (re-fragment for PV) ----
#pragma unroll
        for (int nt = 0; nt < 4; ++nt)
#pragma unroll
            for (int r = 0; r < 4; ++r)
                p_lds[wave][lg * 4 + r][nt * 16 + lm] = __float2bfloat16(pv[nt][r]);
        __syncthreads();   // v_lds staged + (compiler drains lgkm before barrier) p_lds visible

        // ---- O += P @ V ----
#pragma unroll
        for (int kc = 0; kc < 2; ++kc) {
            bf16x8 pf = *reinterpret_cast<const bf16x8*>(&p_lds[wave][lm][kc * 32 + lg * 8]);
#pragma unroll
            for (int dn = 0; dn < 4; ++dn) {
                bf16x8 vf = *reinterpret_cast<const bf16x8*>(&v_lds[dn * 16 + lm][kc * 32 + lg * 8]);
                o[dn] = __builtin_amdgcn_mfma_f32_16x16x32_bf16(pf, vf, o[dn], 0, 0, 0);
            }
        }
    }

    // ---- epilogue: normalize and store [B,H,S,D] f32 ----
#pragma unroll
    for (int dn = 0; dn < 4; ++dn)
#pragma unroll
        for (int r = 0; r < 4; ++r) {
            const int q = q0 + lg * 4 + r;
            out[((size_t)bh * SS + q) * DD + dn * 16 + lm] = o[dn][r] / l_r[r];
        }
}

extern "C" void kernel_launch(void* const* d_in, const int* in_sizes, int n_in,
                              void* d_out, int out_size, void* d_ws, size_t ws_size,
                              hipStream_t stream) {
    const float* xq        = (const float*)d_in[0];
    const float* xk        = (const float*)d_in[1];
    const float* xv        = (const float*)d_in[2];
    const float* mask      = (const float*)d_in[3];
    const float* inv_scale = (const float*)d_in[4];
    const float* Wq        = (const float*)d_in[5];
    const float* bq        = (const float*)d_in[6];
    const float* Wk        = (const float*)d_in[7];
    const float* bk        = (const float*)d_in[8];
    const float* Wv        = (const float*)d_in[9];
    const float* bv        = (const float*)d_in[10];

    __hip_bfloat16* Qp = (__hip_bfloat16*)d_ws;
    __hip_bfloat16* Kp = Qp + (size_t)BB * HH * SS * DD;
    __hip_bfloat16* Vp = Kp + (size_t)BB * HH * SS * DD;
    float* out = (float*)d_out;

    proj_kernel<<<dim3((BB * SS * HH) / 64), dim3(256), 0, stream>>>(
        xq, xk, xv, Wq, bq, Wk, bk, Wv, bv, Qp, Kp, Vp);

    attn_kernel<<<dim3(BB * HH, SS / 64), dim3(256), 0, stream>>>(
        Qp, Kp, Vp, mask, inv_scale, out);
}

// Round 3
// 287.833 us; speedup vs baseline: 1.0623x; 1.0623x over previous
//
#include <hip/hip_runtime.h>
#include <hip/hip_bf16.h>

#define BB 2
#define SS 2048
#define HH 16
#define DD 64

typedef __bf16 bf16x8 __attribute__((ext_vector_type(8)));
typedef float f32x4 __attribute__((ext_vector_type(4)));

// ---------------------------------------------------------------------------
// Kernel 1: fused Q/K/V projection + V transpose + Q pre-scaling.
// grid = (B*H, S/64), block = 256.  Block owns (b, h, 64 consecutive s).
//   Q, K  -> [B,H,S,D] bf16 (row-major, Q pre-multiplied by 1/inv_scale)
//   V     -> Vt [B,H,D,S] bf16 (transposed, for direct PV B-fragment loads)
// ---------------------------------------------------------------------------
__global__ __launch_bounds__(256) void proj_kernel(
    const float* __restrict__ xq, const float* __restrict__ xk,
    const float* __restrict__ xv,
    const float* __restrict__ Wq, const float* __restrict__ bq,
    const float* __restrict__ Wk, const float* __restrict__ bk,
    const float* __restrict__ Wv, const float* __restrict__ bv,
    const float* __restrict__ inv_scale_p,
    __hip_bfloat16* __restrict__ Qp, __hip_bfloat16* __restrict__ Kp,
    __hip_bfloat16* __restrict__ Vt)
{
    __shared__ float w_lds[64][65];                                  // [d][e]
    __shared__ __attribute__((aligned(16))) float x_lds[64][72];     // [row][d]
    __shared__ __attribute__((aligned(16))) __hip_bfloat16 vt_lds[64][72]; // [e][row]

    const int tid = threadIdx.x;
    const int bh = blockIdx.x;
    const int b = bh >> 4, h = bh & 15;
    const int s0 = blockIdx.y * 64;
    const int e = tid & 63;
    const int rg = tid >> 6;
    const float qscale = 1.0f / inv_scale_p[0];

    const float* xs[3] = {xq, xk, xv};
    const float* Ws[3] = {Wq, Wk, Wv};
    const float* Bs[3] = {bq, bk, bv};

#pragma unroll
    for (int m = 0; m < 3; ++m) {
        __syncthreads();   // previous phase's LDS readers done
        // ---- stage W transposed: w_lds[d][e] = W[e][d] (coalesced, pad-65) ----
#pragma unroll
        for (int k = 0; k < 16; ++k) {
            const int i = tid + k * 256;
            w_lds[i & 63][i >> 6] = Ws[m][i];
        }
        // ---- stage x tile: 64 rows x 64 f32, vectorized float4 ----
        {
            const int row = tid >> 2, f0 = tid & 3;
            const float* xrow = xs[m] + ((size_t)((b * SS + s0 + row) * HH + h)) * DD;
            float4* dst = (float4*)&x_lds[row][0];
            const float4* src = (const float4*)xrow;
#pragma unroll
            for (int j = 0; j < 4; ++j) dst[f0 + 4 * j] = src[f0 + 4 * j];
        }
        const float bias_e = Bs[m][e];
        __syncthreads();

        // ---- compute: thread (e, rg) does 16 rows, f32 FMA ----
        float acc[16];
#pragma unroll
        for (int it = 0; it < 16; ++it) acc[it] = bias_e;
#pragma unroll
        for (int dq = 0; dq < 16; ++dq) {
            const float w0 = w_lds[dq * 4 + 0][e];
            const float w1 = w_lds[dq * 4 + 1][e];
            const float w2 = w_lds[dq * 4 + 2][e];
            const float w3 = w_lds[dq * 4 + 3][e];
#pragma unroll
            for (int it = 0; it < 16; ++it) {
                const float4 x4 = *(const float4*)&x_lds[rg * 16 + it][dq * 4];
                acc[it] = fmaf(x4.x, w0, fmaf(x4.y, w1, fmaf(x4.z, w2, fmaf(x4.w, w3, acc[it]))));
            }
        }

        if (m == 0) {
#pragma unroll
            for (int it = 0; it < 16; ++it)
                Qp[((size_t)bh * SS + s0 + rg * 16 + it) * DD + e] =
                    __float2bfloat16(acc[it] * qscale);
        } else if (m == 1) {
#pragma unroll
            for (int it = 0; it < 16; ++it)
                Kp[((size_t)bh * SS + s0 + rg * 16 + it) * DD + e] =
                    __float2bfloat16(acc[it]);
        } else {
            // transpose through LDS, then vectorized global write of Vt rows
#pragma unroll
            for (int it = 0; it < 16; ++it)
                vt_lds[e][rg * 16 + it] = __float2bfloat16(acc[it]);
            __syncthreads();
            // 4 threads per row, each writes TWO bf16x8 (16 elems) = full 64-row
            const int row2 = tid >> 2, f = tid & 3;   // row2 = d index
            bf16x8 vv0 = *(const bf16x8*)&vt_lds[row2][f * 16];
            bf16x8 vv1 = *(const bf16x8*)&vt_lds[row2][f * 16 + 8];
            __hip_bfloat16* dst = &Vt[((size_t)bh * DD + row2) * SS + s0 + f * 16];
            *(bf16x8*)dst = vv0;
            *(bf16x8*)(dst + 8) = vv1;
        }
    }
}

// ---------------------------------------------------------------------------
// Kernel 2: flash attention, barrier-free.  All fragments from global (L2):
// K row-major, V from Vt.  Only wave-private p_lds re-fragmentation in LDS.
// grid = (B*H, S/64); block = 256 (4 independent waves, 16 q-rows each).
// ---------------------------------------------------------------------------
__global__ __launch_bounds__(256) void attn_kernel(
    const __hip_bfloat16* __restrict__ Qp, const __hip_bfloat16* __restrict__ Kp,
    const __hip_bfloat16* __restrict__ Vt, const float* __restrict__ mask,
    float* __restrict__ out)
{
    constexpr int TT = 64;
    constexpr int VP = TT + 8;
    __shared__ __attribute__((aligned(16))) __hip_bfloat16 p_lds[4][16][VP];

    const int tid = threadIdx.x;
    const int lane = tid & 63;
    const int wave = tid >> 6;
    const int lm = lane & 15;
    const int lg = lane >> 4;
    const int bh = blockIdx.x;
    const int qt = blockIdx.y;
    const int b = bh >> 4;

    const __hip_bfloat16* Qb = Qp + (size_t)bh * SS * DD;
    const __hip_bfloat16* Kb = Kp + (size_t)bh * SS * DD;
    const __hip_bfloat16* Vtb = Vt + (size_t)bh * DD * SS;

    const int q0 = qt * 64 + wave * 16;
    const float* mrow[4];
#pragma unroll
    for (int r = 0; r < 4; ++r)
        mrow[r] = mask + (size_t)b * SS * SS + (size_t)(q0 + lg * 4 + r) * SS;

    // Q fragments (already pre-scaled by 1/inv_scale in proj)
    bf16x8 qf[2];
    {
        const __hip_bfloat16* qptr = Qb + (size_t)(q0 + lm) * DD + lg * 8;
        qf[0] = *reinterpret_cast<const bf16x8*>(qptr);
        qf[1] = *reinterpret_cast<const bf16x8*>(qptr + 32);
    }

    f32x4 o[4];
    float m_r[4], l_r[4];
#pragma unroll
    for (int i = 0; i < 4; ++i) { o[i] = f32x4{0.f, 0.f, 0.f, 0.f}; m_r[i] = -1e30f; l_r[i] = 0.f; }

    for (int t0 = 0; t0 < SS; t0 += TT) {
        // ---- QK^T: S[q][t] = sum_d Q[q][d] K[t][d] ----
        f32x4 s[4];
#pragma unroll
        for (int nt = 0; nt < 4; ++nt) s[nt] = f32x4{0.f, 0.f, 0.f, 0.f};
#pragma unroll
        for (int kc = 0; kc < 2; ++kc)
#pragma unroll
            for (int nt = 0; nt < 4; ++nt) {
                bf16x8 kf = *reinterpret_cast<const bf16x8*>(
                    Kb + (size_t)(t0 + nt * 16 + lm) * DD + kc * 32 + lg * 8);
                s[nt] = __builtin_amdgcn_mfma_f32_16x16x32_bf16(qf[kc], kf, s[nt], 0, 0, 0);
            }

        // ---- V fragments for this tile (independent of softmax; issue early) ----
        bf16x8 vr[8];
#pragma unroll
        for (int kc = 0; kc < 2; ++kc)
#pragma unroll
            for (int dn = 0; dn < 4; ++dn)
                vr[kc * 4 + dn] = *reinterpret_cast<const bf16x8*>(
                    Vtb + (size_t)(dn * 16 + lm) * SS + t0 + kc * 32 + lg * 8);

        // ---- mask add.  C layout: col = lane&15 (t), row = lg*4+r (q) ----
        float sv[4][4];
#pragma unroll
        for (int nt = 0; nt < 4; ++nt)
#pragma unroll
            for (int r = 0; r < 4; ++r)
                sv[nt][r] = s[nt][r] + mrow[r][t0 + nt * 16 + lm];

        // ---- online softmax update ----
        float pv[4][4];
#pragma unroll
        for (int r = 0; r < 4; ++r) {
            float mx = fmaxf(fmaxf(sv[0][r], sv[1][r]), fmaxf(sv[2][r], sv[3][r]));
#pragma unroll
            for (int off = 1; off < 16; off <<= 1) mx = fmaxf(mx, __shfl_xor(mx, off));
            const float mn = fmaxf(m_r[r], mx);
            const float alpha = __expf(m_r[r] - mn);
            m_r[r] = mn;
            float rs = 0.f;
#pragma unroll
            for (int nt = 0; nt < 4; ++nt) {
                const float p = __expf(sv[nt][r] - mn);
                pv[nt][r] = p;
                rs += p;
            }
#pragma unroll
            for (int off = 1; off < 16; off <<= 1) rs += __shfl_xor(rs, off);
            l_r[r] = l_r[r] * alpha + rs;
            o[0][r] *= alpha; o[1][r] *= alpha; o[2][r] *= alpha; o[3][r] *= alpha;
        }

        // ---- P re-fragmentation through wave-private LDS (no barrier) ----
#pragma unroll
        for (int nt = 0; nt < 4; ++nt)
#pragma unroll
            for (int r = 0; r < 4; ++r)
                p_lds[wave][lg * 4 + r][nt * 16 + lm] = __float2bfloat16(pv[nt][r]);

        // ---- O += P @ V ----
#pragma unroll
        for (int kc = 0; kc < 2; ++kc) {
            bf16x8 pf = *reinterpret_cast<const bf16x8*>(&p_lds[wave][lm][kc * 32 + lg * 8]);
#pragma unroll
            for (int dn = 0; dn < 4; ++dn)
                o[dn] = __builtin_amdgcn_mfma_f32_16x16x32_bf16(pf, vr[kc * 4 + dn], o[dn], 0, 0, 0);
        }
    }

    // ---- epilogue: normalize and store [B,H,S,D] f32 ----
#pragma unroll
    for (int dn = 0; dn < 4; ++dn)
#pragma unroll
        for (int r = 0; r < 4; ++r) {
            const int q = q0 + lg * 4 + r;
            out[((size_t)bh * SS + q) * DD + dn * 16 + lm] = o[dn][r] / l_r[r];
        }
}

extern "C" void kernel_launch(void* const* d_in, const int* in_sizes, int n_in,
                              void* d_out, int out_size, void* d_ws, size_t ws_size,
                              hipStream_t stream) {
    const float* xq        = (const float*)d_in[0];
    const float* xk        = (const float*)d_in[1];
    const float* xv        = (const float*)d_in[2];
    const float* mask      = (const float*)d_in[3];
    const float* inv_scale = (const float*)d_in[4];
    const float* Wq        = (const float*)d_in[5];
    const float* bq        = (const float*)d_in[6];
    const float* Wk        = (const float*)d_in[7];
    const float* bk        = (const float*)d_in[8];
    const float* Wv        = (const float*)d_in[9];
    const float* bv        = (const float*)d_in[10];

    __hip_bfloat16* Qp = (__hip_bfloat16*)d_ws;
    __hip_bfloat16* Kp = Qp + (size_t)BB * HH * SS * DD;
    __hip_bfloat16* Vt = Kp + (size_t)BB * HH * SS * DD;
    float* out = (float*)d_out;

    proj_kernel<<<dim3(BB * HH, SS / 64), dim3(256), 0, stream>>>(
        xq, xk, xv, Wq, bq, Wk, bk, Wv, bv, inv_scale, Qp, Kp, Vt);

    attn_kernel<<<dim3(BB * HH, SS / 64), dim3(256), 0, stream>>>(
        Qp, Kp, Vt, mask, out);
}